// Round 8
// baseline (250.480 us; speedup 1.0000x reference)
//
#include <hip/hip_runtime.h>
#include <math.h>

#define NROWS 65536
#define DIM   256
#define KCB   1024
#define TM    64
#define NBLK  (NROWS / TM)     // 1024
#define QOFF  (NROWS * DIM)
#define IDXOFF (QOFF + 1)

// ws float layout
#define WS_DMIN 0
#define WS_PLP  1
#define WS_AVGP 4                        // 8 replicas x 1024 floats (atomic contention /8)
#define WS_C2   (WS_AVGP + 8 * 1024)
#define WS_CBF  (WS_C2 + 1024)           // fragment-ordered hi-bf16 codebook, 131072 ushort

#define DELTA 0.05f
#define XPITCH 260                       // fp32 LDS x pitch (floats)

typedef __attribute__((ext_vector_type(8))) __bf16 bf16x8;
typedef __attribute__((ext_vector_type(4))) float  f32x4;
typedef __attribute__((ext_vector_type(8))) unsigned short u16x8;

// epilogue LDS float offsets (static shared, 5504 floats = 22016 B)
#define EP_REDD 0       // [8][64]
#define EP_REDK 512     // [8][64] int
#define EP_RT1  1024    // [8][64]
#define EP_RT2  1536    // [8][64]
#define EP_GMIN 2048    // 64
#define EP_CNT  2112    // 64 int
#define EP_CAND 2176    // 64*16 int
#define EP_CEX  3200    // 64*16
#define EP_R1F  4224    // 64
#define EP_SP   4288    // 64
#define EP_KFIN 4352    // 64 int
#define EP_DFIN 4416    // 64
#define EP_AVGP 4480    // 1024
#define EP_SIZE 5504

__device__ __forceinline__ unsigned short f2bf(float f) {
    unsigned u = __float_as_uint(f);
    u += 0x7fffu + ((u >> 16) & 1u);
    return (unsigned short)(u >> 16);
}

__device__ __forceinline__ bf16x8 cvt8(const float* src) {
    float4 v0 = *(const float4*)src, v1 = *(const float4*)(src + 4);
    u16x8 o;
    o[0] = f2bf(v0.x); o[1] = f2bf(v0.y); o[2] = f2bf(v0.z); o[3] = f2bf(v0.w);
    o[4] = f2bf(v1.x); o[5] = f2bf(v1.y); o[6] = f2bf(v1.z); o[7] = f2bf(v1.w);
    return __builtin_bit_cast(bf16x8, o);
}

// async global->LDS DMA, 16 B per lane; lds dest = wave-uniform base + lane*16
__device__ __forceinline__ void gload_lds16(const void* g, void* l) {
    __builtin_amdgcn_global_load_lds(
        (const __attribute__((address_space(1))) unsigned int*)g,
        (__attribute__((address_space(3))) unsigned int*)l, 16, 0, 0);
}

// ---------------- prep: coalesced, 128 blocks ----------------
// Fragment layout (bank-conflict-free read): global chunk index =
//   sub*2048 + wc*256 + ct*64 + qq*16 + m,   sub = kc*2 + h
// where codebook row k = h*512 + wc*64 + ct*16 + m. A wave's ds_read_b128 at a given
// (wc, ct) then touches lane-consecutive 16 B addresses -> conflict-free.
__global__ __launch_bounds__(256) void prep_kernel(const float* __restrict__ cb,
                                                   float* __restrict__ ws) {
    int gid = blockIdx.x * 256 + threadIdx.x;   // 0..32767
    if (gid < 4) ws[gid] = 0.f;
    if (gid < 8192) ws[WS_AVGP + gid] = 0.f;    // 8x1024 replica region

    int k  = gid >> 5;
    int s  = gid & 31;
    int kc = s >> 2;
    int qq = s & 3;

    if (gid < 1024) {
        // c2 on the EXACT round-1 grid (sequential float4 chain), one thread per row
        const float4* row = (const float4*)(cb + (size_t)gid * DIM);
        float ssum = 0.f;
#pragma unroll 8
        for (int i = 0; i < DIM / 4; ++i) {
            float4 v = row[i];
            ssum += v.x * v.x + v.y * v.y + v.z * v.z + v.w * v.w;
        }
        ws[WS_C2 + gid] = ssum;
    }

    int h  = k >> 9;
    int wc = (k >> 6) & 7;
    int ct = (k >> 4) & 3;
    int m  = k & 15;
    int sub = (kc << 1) + h;
    size_t chunk = ((size_t)sub << 11) + (wc << 8) + (ct << 6) + (qq << 4) + m;

    unsigned short* cbf = (unsigned short*)(ws + WS_CBF);
    const float* src = cb + (size_t)k * DIM + (kc << 5) + (qq << 3);
    float4 v0 = *(const float4*)src, v1 = *(const float4*)(src + 4);
    u16x8 o;
    o[0] = f2bf(v0.x); o[1] = f2bf(v0.y); o[2] = f2bf(v0.z); o[3] = f2bf(v0.w);
    o[4] = f2bf(v1.x); o[5] = f2bf(v1.y); o[6] = f2bf(v1.z); o[7] = f2bf(v1.w);
    *(u16x8*)(cbf + chunk * 8) = o;
}

// ---------------- main fused kernel ----------------
// TM=64 / 1024 threads (16 waves = 2 row-halves x 8 col-groups).
// B staged through LDS via global_load_lds (32 KB/sub, double-buffered), one copy per
// block; fragment order is lane-linear -> conflict-free ds_read_b128.
// x staged once in LDS as fp32; A-fragments use in-loop cvt8 (bit-identical path).
__global__ __launch_bounds__(1024, 4) void vq_main(const float* __restrict__ x,
                                                   const float* __restrict__ cb,
                                                   float* __restrict__ ws,
                                                   float* __restrict__ out) {
    __shared__ float epi[EP_SIZE];
    __shared__ float xs[64 * XPITCH];       // 66560 B fp32 x tile
    __shared__ u16x8 ldsB[2][2048];         // 65536 B B double buffer (32 KB each)

    const int tid  = threadIdx.x;
    const int w    = tid >> 6;       // 0..15
    const int lane = tid & 63;
    const int m    = lane & 15;
    const int q    = lane >> 4;
    const int wc   = w & 7;          // column group
    const int rh   = w >> 3;         // row half
    const int R0   = blockIdx.x * TM;

    const char* gB = (const char*)(ws + WS_CBF);   // fragment-ordered codebook base
    // in-sub chunk = wc*256 + ct*64 + lane  (ct step 64) -> lane-linear 16 B reads
    const int fragoff = (wc << 8) + lane;

    bf16x8 ah[2];

    // ---- stage x rows (wave w -> rows 4w..4w+3); HBM loads issued first
    float4 t0 = *((const float4*)(x + (size_t)(R0 + (w << 2) + 0) * DIM) + lane);
    float4 t1 = *((const float4*)(x + (size_t)(R0 + (w << 2) + 1) * DIM) + lane);
    float4 t2 = *((const float4*)(x + (size_t)(R0 + (w << 2) + 2) * DIM) + lane);
    float4 t3 = *((const float4*)(x + (size_t)(R0 + (w << 2) + 3) * DIM) + lane);

    // stage sub 0 into buf0 (async DMA, overlaps the x loads)
    {
        const char* g = gB + (size_t)tid * 16;
        char* l = (char*)&ldsB[0][0] + (w << 10);
        gload_lds16(g, l);
        gload_lds16(g + 16384, l + 16384);
    }

    *((float4*)(xs + ((w << 2) + 0) * XPITCH) + lane) = t0;
    *((float4*)(xs + ((w << 2) + 1) * XPITCH) + lane) = t1;
    *((float4*)(xs + ((w << 2) + 2) * XPITCH) + lane) = t2;
    *((float4*)(xs + ((w << 2) + 3) * XPITCH) + lane) = t3;

    f32x4 acc[2][8];
#pragma unroll
    for (int a = 0; a < 2; ++a)
#pragma unroll
        for (int b = 0; b < 8; ++b) acc[a][b] = (f32x4)0.f;

    __syncthreads();   // drains staging DMA (vmcnt) + xs writes (lgkm)

    const int rbase = rh << 5;       // wave's 32-row base inside the LDS tile
    ah[0] = cvt8(xs + (rbase + m) * XPITCH + (q << 3));
    ah[1] = cvt8(xs + (rbase + 16 + m) * XPITCH + (q << 3));

#pragma unroll
    for (int sub = 0; sub < 16; ++sub) {
        const int cur = sub & 1;
        if (sub < 15) {
            // async-stage sub+1 into the other buffer
            const char* g = gB + (size_t)(sub + 1) * 32768 + (size_t)tid * 16;
            char* l = (char*)&ldsB[cur ^ 1][0] + (w << 10);
            gload_lds16(g, l);
            gload_lds16(g + 16384, l + 16384);
        }
        const u16x8* lbc = &ldsB[cur][fragoff];
        u16x8 f0 = lbc[0], f1 = lbc[64], f2 = lbc[128], f3 = lbc[192];
#pragma unroll
        for (int ct = 0; ct < 4; ++ct) {
            u16x8 fr = (ct == 0) ? f0 : (ct == 1) ? f1 : (ct == 2) ? f2 : f3;
            bf16x8 bh = __builtin_bit_cast(bf16x8, fr);
            int cg = ((sub & 1) << 2) + ct;
            acc[0][cg] = __builtin_amdgcn_mfma_f32_16x16x32_bf16(ah[0], bh, acc[0][cg], 0, 0, 0);
            acc[1][cg] = __builtin_amdgcn_mfma_f32_16x16x32_bf16(ah[1], bh, acc[1][cg], 0, 0, 0);
        }
        if ((sub & 1) == 1 && sub < 15) {
            const int nkc = (sub >> 1) + 1;
            ah[0] = cvt8(xs + (rbase + m) * XPITCH + (nkc << 5) + (q << 3));
            ah[1] = cvt8(xs + (rbase + 16 + m) * XPITCH + (nkc << 5) + (q << 3));
        }
        if (sub < 15) __syncthreads();   // staging of sub+1 complete & visible
    }

    // ================= epilogue (rows = 64) =================
    // E0: zero accumulators; g = c2 - 2*acc (screen grid); per-wave per-row argmin
    if (tid < 64) ((int*)(epi + EP_CNT))[tid] = 0;
    epi[EP_AVGP + tid] = 0.f;            // 1024 threads, one each

    float c2v[8];
#pragma unroll
    for (int cg = 0; cg < 8; ++cg) {
        int col = ((cg >> 2) << 9) + (wc << 6) + ((cg & 3) << 4) + m;
        c2v[cg] = ws[WS_C2 + col];
    }
#pragma unroll
    for (int rt = 0; rt < 2; ++rt) {
#pragma unroll
        for (int reg = 0; reg < 4; ++reg) {
            int row = rbase + (rt << 4) + (q << 2) + reg;
            float md = 3.0e38f; int mk = 0;
#pragma unroll
            for (int cg = 0; cg < 8; ++cg) {
                float g = c2v[cg] - 2.0f * acc[rt][cg][reg];
                acc[rt][cg][reg] = g;
                int col = ((cg >> 2) << 9) + (wc << 6) + ((cg & 3) << 4) + m;
                if (g < md) { md = g; mk = col; }
            }
#pragma unroll
            for (int off = 1; off <= 8; off <<= 1) {
                float od = __shfl_xor(md, off, 64);
                int   ok = __shfl_xor(mk, off, 64);
                if (od < md || (od == md && ok < mk)) { md = od; mk = ok; }
            }
            if (m == 0) {
                epi[EP_REDD + (wc << 6) + row] = md;
                ((int*)(epi + EP_REDK))[(wc << 6) + row] = mk;
            }
        }
    }
    __syncthreads();

    // E1: cross-group min per row
    if (tid < 64) {
        float gm = 3.0e38f;
#pragma unroll
        for (int g = 0; g < 8; ++g) {
            float d = epi[EP_REDD + (g << 6) + tid];
            if (d < gm) gm = d;
        }
        epi[EP_GMIN + tid] = gm;
    }
    __syncthreads();

    // E2: exp pass + candidate collection + per-wave T1/T2
    {
        int* cnt  = (int*)(epi + EP_CNT);
        int* cand = (int*)(epi + EP_CAND);
#pragma unroll
        for (int rt = 0; rt < 2; ++rt) {
#pragma unroll
            for (int reg = 0; reg < 4; ++reg) {
                int row = rbase + (rt << 4) + (q << 2) + reg;
                float gm = epi[EP_GMIN + row];
                float t1 = 0.f, t2 = 0.f;
#pragma unroll
                for (int cg = 0; cg < 8; ++cg) {
                    float g = acc[rt][cg][reg];
                    if (g < gm + DELTA) {
                        int col = ((cg >> 2) << 9) + (wc << 6) + ((cg & 3) << 4) + m;
                        int pos = atomicAdd(&cnt[row], 1);
                        if (pos < 16) cand[(row << 4) + pos] = col;
                    }
                    float z = -100.0f * (g - gm);
                    float e = __expf(z);
                    acc[rt][cg][reg] = e;
                    t1 += e;
                    t2 += e * z;
                }
#pragma unroll
                for (int off = 1; off <= 8; off <<= 1) {
                    t1 += __shfl_xor(t1, off, 64);
                    t2 += __shfl_xor(t2, off, 64);
                }
                if (m == 0) {
                    epi[EP_RT1 + (wc << 6) + row] = t1;
                    epi[EP_RT2 + (wc << 6) + row] = t2;
                }
            }
        }
    }
    __syncthreads();

    // E3: finalize per-row softmax stats
    if (tid < 64) {
        float T1 = 0.f, T2 = 0.f;
#pragma unroll
        for (int g = 0; g < 8; ++g) {
            T1 += epi[EP_RT1 + (g << 6) + tid];
            T2 += epi[EP_RT2 + (g << 6) + tid];
        }
        float r1 = 1.0f / T1;
        epi[EP_R1F + tid] = r1;
        epi[EP_SP + tid]  = T2 * r1 - logf(T1);
    }
    __syncthreads();

    // E4a: avg_probs column sums (row-halves combined with a staggered += across barriers)
    float sv[8];
    {
        float r1v[2][4];
#pragma unroll
        for (int rt = 0; rt < 2; ++rt)
#pragma unroll
            for (int reg = 0; reg < 4; ++reg)
                r1v[rt][reg] = epi[EP_R1F + rbase + (rt << 4) + (q << 2) + reg];
#pragma unroll
        for (int cg = 0; cg < 8; ++cg) {
            float s = 0.f;
#pragma unroll
            for (int rt = 0; rt < 2; ++rt)
#pragma unroll
                for (int reg = 0; reg < 4; ++reg)
                    s += acc[rt][cg][reg] * r1v[rt][reg];
            s += __shfl_xor(s, 16, 64);
            s += __shfl_xor(s, 32, 64);
            sv[cg] = s;
        }
        if (rh == 0 && lane < 16) {
#pragma unroll
            for (int cg = 0; cg < 8; ++cg) {
                int col = ((cg >> 2) << 9) + (wc << 6) + ((cg & 3) << 4) + m;
                epi[EP_AVGP + col] += sv[cg];
            }
        }
    }
    // E4b: candidate refinement on the EXACT round-1/np grid:
    //      d = (x2 - 2*ab) + c2; ab sequential fmaf chain; ax from fp32 LDS; unrolled.
    {
        int* cnt  = (int*)(epi + EP_CNT);
        int* cand = (int*)(epi + EP_CAND);
        int r = tid >> 4;          // 64 rows x 16 threads = 1024
        int i = tid & 15;
        int n = cnt[r]; if (n > 16) n = 16;
        if (i < n) {
            int k = cand[(r << 4) + i];
            const float4* ax = (const float4*)(xs + r * XPITCH);
            const float4* bx = (const float4*)(cb + (((size_t)k) << 8));
            float ab = 0.f, x2 = 0.f;
#pragma unroll 8
            for (int d4 = 0; d4 < 64; ++d4) {
                float4 a = ax[d4], b = bx[d4];
                ab = fmaf(a.x, b.x, ab);
                ab = fmaf(a.y, b.y, ab);
                ab = fmaf(a.z, b.z, ab);
                ab = fmaf(a.w, b.w, ab);
                x2 += a.x * a.x + a.y * a.y + a.z * a.z + a.w * a.w;
            }
            float t = 2.0f * ab;
            epi[EP_CEX + (r << 4) + i] = (x2 - t) + ws[WS_C2 + k];
        }
    }
    __syncthreads();

    // second half of E4a (race-free via the barrier above)
    if (rh == 1 && lane < 16) {
#pragma unroll
        for (int cg = 0; cg < 8; ++cg) {
            int col = ((cg >> 2) << 9) + (wc << 6) + ((cg & 3) << 4) + m;
            epi[EP_AVGP + col] += sv[cg];
        }
    }

    // E5: final per-row selection (min d, lowest-index tie-break) + index output
    if (tid < 64) {
        int* cnt  = (int*)(epi + EP_CNT);
        int* cand = (int*)(epi + EP_CAND);
        int n = cnt[tid]; if (n > 16) n = 16;
        float bd = epi[EP_CEX + (tid << 4)];
        int   bk = cand[(tid << 4)];
        for (int i = 1; i < n; ++i) {
            float d = epi[EP_CEX + (tid << 4) + i];
            int   k = cand[(tid << 4) + i];
            if (d < bd || (d == bd && k < bk)) { bd = d; bk = k; }
        }
        ((int*)(epi + EP_KFIN))[tid] = bk;
        epi[EP_DFIN + tid] = bd;
        out[IDXOFF + R0 + tid] = (float)bk;
    }
    __syncthreads();

    // E6: quantized gather (wave w -> rows w*4..w*4+3, nt stores), global accumulators
#pragma unroll
    for (int rr = 0; rr < 4; ++rr) {
        int r = (w << 2) + rr;
        int k = ((int*)(epi + EP_KFIN))[r];
        f32x4 v = *((const f32x4*)(cb + (((size_t)k) << 8)) + lane);
        __builtin_nontemporal_store(v, (f32x4*)(out + (((size_t)(R0 + r)) << 8)) + lane);
    }
    // replicated avg_probs accumulator: contention /8
    atomicAdd(ws + WS_AVGP + ((blockIdx.x & 7) << 10) + tid, epi[EP_AVGP + tid]);
    if (tid < 64) {
        float sp = epi[EP_SP + tid];
        float dd = epi[EP_DFIN + tid];
#pragma unroll
        for (int off = 1; off <= 32; off <<= 1) {
            sp += __shfl_xor(sp, off, 64);
            dd += __shfl_xor(dd, off, 64);
        }
        if (tid == 0) {
            atomicAdd(ws + WS_PLP, sp);
            atomicAdd(ws + WS_DMIN, dd);
        }
    }
}

// ---------------- finalize ----------------
__global__ __launch_bounds__(256) void vq_finalize(const float* __restrict__ ws,
                                                   float* __restrict__ out) {
    __shared__ float red[4];
    int tid = threadIdx.x;
    float part = 0.f;
    for (int k = tid; k < 1024; k += 256) {
        float s = 0.f;
#pragma unroll
        for (int r = 0; r < 8; ++r) s += ws[WS_AVGP + (r << 10) + k];
        float ap = s * (1.0f / 65536.0f);
        part += ap * logf(ap + 1e-5f);
    }
#pragma unroll
    for (int off = 32; off; off >>= 1) part += __shfl_xor(part, off, 64);
    if ((tid & 63) == 0) red[tid >> 6] = part;
    __syncthreads();
    if (tid == 0) {
        float sum_aplog      = red[0] + red[1] + red[2] + red[3];
        float avg_entropy    = -sum_aplog;
        float sample_entropy = -ws[WS_PLP] * (1.0f / 65536.0f);
        float entropy_loss   = (sample_entropy - avg_entropy) * 0.1f;
        float eq = 1.25f * ws[WS_DMIN] * (1.0f / ((float)NROWS * (float)DIM));
        out[QOFF] = eq + entropy_loss;
    }
}

extern "C" void kernel_launch(void* const* d_in, const int* in_sizes, int n_in,
                              void* d_out, int out_size, void* d_ws, size_t ws_size,
                              hipStream_t stream) {
    const float* x  = (const float*)d_in[0];
    const float* cb = (const float*)d_in[1];
    float* out = (float*)d_out;
    float* ws  = (float*)d_ws;

    prep_kernel<<<128, 256, 0, stream>>>(cb, ws);
    vq_main<<<NBLK, 1024, 0, stream>>>(x, cb, ws, out);
    vq_finalize<<<1, 256, 0, stream>>>(ws, out);
}